// Round 2
// baseline (325.913 us; speedup 1.0000x reference)
//
#include <hip/hip_runtime.h>
#include <hip/hip_bf16.h>
#include <stdint.h>

// ReconBlock: 3-axis 3-tap submanifold conv (gathered neighbors) + BN(inference)
// + sigmoid per branch, branches summed, gated by input features.
// dtypes (per reference): all float arrays fp32, nbr_* int32, out fp32.
// Compute path: fp32 -> bf16 (round) -> mfma_f32_16x16x32_bf16 -> fp32 epilogue.

typedef __attribute__((ext_vector_type(8))) __bf16 bf16x8;
typedef __attribute__((ext_vector_type(8))) unsigned short u16x8;
typedef __attribute__((ext_vector_type(4))) float f32x4;
typedef __attribute__((ext_vector_type(2))) float f32x2;

constexpr int NVOX    = 1000000;
constexpr int NTILES  = NVOX / 16;                  // 62500 (exact)
constexpr int TPW     = 8;                          // tiles per wave
constexpr int WPB     = 4;                          // waves per block (256 thr)
constexpr int NWAVES  = (NTILES + TPW - 1) / TPW;   // 7813
constexpr int NBLOCKS = (NWAVES + WPB - 1) / WPB;   // 1954

__device__ __forceinline__ unsigned short f2bf_rn(float f) {
    union { float f; unsigned int u; } c; c.f = f;
    return (unsigned short)((c.u + 0x8000u) >> 16);   // round-half-up to bf16
}

__device__ __forceinline__ bf16x8 cvt_frag(f32x4 lo, f32x4 hi) {
    u16x8 r;
    #pragma unroll
    for (int i = 0; i < 4; ++i) {
        r[i]     = f2bf_rn(lo[i]);
        r[i + 4] = f2bf_rn(hi[i]);
    }
    return __builtin_bit_cast(bf16x8, r);
}

__global__ __launch_bounds__(256) void recon_kernel(
    const float* __restrict__ feat,   // [N][32] fp32
    const int*   __restrict__ nprev,  // [3][N]
    const int*   __restrict__ nnext,  // [3][N]
    const float* __restrict__ Wt,     // [3][3][32][32] fp32
    const float* __restrict__ gma,    // [3][32]
    const float* __restrict__ bta,
    const float* __restrict__ mea,
    const float* __restrict__ var,
    float*       __restrict__ out)    // [N][32] fp32
{
    const int lane = threadIdx.x & 63;
    const int n    = lane & 15;   // lane column coord (owns out channels 2n, 2n+1)
    const int quad = lane >> 4;   // k-block / output-row-block coord

    // XCD-aware swizzle: contiguous 1/8th of the voxel range per XCD so the
    // far (z-axis) neighbor gathers stay within one XCD's L2 stream window.
    int b   = blockIdx.x;
    int per = NBLOCKS / 8;                                  // 244
    int bs  = (b < per * 8) ? ((b & 7) * per + (b >> 3)) : b;
    int wv  = bs * WPB + (threadIdx.x >> 6);

    const int t0 = wv * TPW;
    if (t0 >= NTILES) return;

    // ---- W in MFMA B-operand layout, bf16, held in regs (72 VGPRs).
    // Column interleave: half h supplies original output-channel 2n+h, so one
    // lane's two accumulators cover adjacent channels (float2 epilogue).
    bf16x8 Bf[3][3][2];
    #pragma unroll
    for (int br = 0; br < 3; ++br)
        #pragma unroll
        for (int t = 0; t < 3; ++t)
            #pragma unroll
            for (int h = 0; h < 2; ++h) {
                u16x8 tmp;
                #pragma unroll
                for (int j = 0; j < 8; ++j) {
                    int k = quad * 8 + j;
                    tmp[j] = f2bf_rn(Wt[((br * 3 + t) * 32 + k) * 32 + 2 * n + h]);
                }
                Bf[br][t][h] = __builtin_bit_cast(bf16x8, tmp);
            }

    // ---- BN constants for this lane's two channels (2n, 2n+1), 3 branches
    float sc[3][2], mn[3][2], bt[3][2];
    #pragma unroll
    for (int br = 0; br < 3; ++br)
        #pragma unroll
        for (int h = 0; h < 2; ++h) {
            int c = 2 * n + h;
            float g = gma[br * 32 + c];
            float v = var[br * 32 + c];
            sc[br][h] = g * __frsqrt_rn(v + 1e-5f);
            mn[br][h] = mea[br * 32 + c];
            bt[br][h] = bta[br * 32 + c];
        }

    // ---- neighbor indices for first tile (prefetched one tile ahead below)
    int ip[3], inx[3];
    {
        int row0 = t0 * 16 + n;
        #pragma unroll
        for (int a = 0; a < 3; ++a) {
            ip[a]  = nprev[a * NVOX + row0];
            inx[a] = nnext[a * NVOX + row0];
        }
    }

    #pragma unroll 1
    for (int tt = 0; tt < TPW; ++tt) {
        int tile = t0 + tt;
        if (tile >= NTILES) return;
        int base = tile * 16;
        int row  = base + n;      // A-row this lane fetches (same for all quads)

        // ---- issue all A loads (self + 3 prev + 3 next), 32 B each
        const f32x4* ps = (const f32x4*)(feat + row * 32 + quad * 8);
        f32x4 s_lo = ps[0], s_hi = ps[1];
        f32x4 p_lo[3], p_hi[3], n_lo[3], n_hi[3];
        #pragma unroll
        for (int a = 0; a < 3; ++a) {
            p_lo[a] = (f32x4){0.f, 0.f, 0.f, 0.f}; p_hi[a] = p_lo[a];
            n_lo[a] = p_lo[a];                     n_hi[a] = p_lo[a];
            if (ip[a] >= 0) {
                const f32x4* pp = (const f32x4*)(feat + ip[a] * 32 + quad * 8);
                p_lo[a] = pp[0]; p_hi[a] = pp[1];
            }
            if (inx[a] >= 0) {
                const f32x4* pn = (const f32x4*)(feat + inx[a] * 32 + quad * 8);
                n_lo[a] = pn[0]; n_hi[a] = pn[1];
            }
        }

        // ---- prefetch next tile's neighbor indices while gathers are in flight
        int ipn[3], inn[3];
        if (tt + 1 < TPW && tile + 1 < NTILES) {
            int nrow = row + 16;
            #pragma unroll
            for (int a = 0; a < 3; ++a) {
                ipn[a] = nprev[a * NVOX + nrow];
                inn[a] = nnext[a * NVOX + nrow];
            }
        } else {
            #pragma unroll
            for (int a = 0; a < 3; ++a) { ipn[a] = -1; inn[a] = -1; }
        }

        // ---- convert to bf16 fragments
        bf16x8 Aself = cvt_frag(s_lo, s_hi);
        bf16x8 Ap[3], An[3];
        #pragma unroll
        for (int a = 0; a < 3; ++a) {
            Ap[a] = cvt_frag(p_lo[a], p_hi[a]);
            An[a] = cvt_frag(n_lo[a], n_hi[a]);
        }

        // ---- 3 branches x (3 taps x 2 col-halves) MFMA, BN+sigmoid, sum
        f32x4 acc0 = {0.f, 0.f, 0.f, 0.f}, acc1 = {0.f, 0.f, 0.f, 0.f};
        #pragma unroll
        for (int br = 0; br < 3; ++br) {
            f32x4 c0 = {0.f, 0.f, 0.f, 0.f}, c1 = {0.f, 0.f, 0.f, 0.f};
            c0 = __builtin_amdgcn_mfma_f32_16x16x32_bf16(Ap[br], Bf[br][0][0], c0, 0, 0, 0);
            c1 = __builtin_amdgcn_mfma_f32_16x16x32_bf16(Ap[br], Bf[br][0][1], c1, 0, 0, 0);
            c0 = __builtin_amdgcn_mfma_f32_16x16x32_bf16(Aself,  Bf[br][1][0], c0, 0, 0, 0);
            c1 = __builtin_amdgcn_mfma_f32_16x16x32_bf16(Aself,  Bf[br][1][1], c1, 0, 0, 0);
            c0 = __builtin_amdgcn_mfma_f32_16x16x32_bf16(An[br], Bf[br][2][0], c0, 0, 0, 0);
            c1 = __builtin_amdgcn_mfma_f32_16x16x32_bf16(An[br], Bf[br][2][1], c1, 0, 0, 0);
            #pragma unroll
            for (int r = 0; r < 4; ++r) {
                float y0 = (c0[r] - mn[br][0]) * sc[br][0] + bt[br][0];
                float y1 = (c1[r] - mn[br][1]) * sc[br][1] + bt[br][1];
                acc0[r] += __builtin_amdgcn_rcpf(1.0f + __expf(-y0));
                acc1[r] += __builtin_amdgcn_rcpf(1.0f + __expf(-y1));
            }
        }

        // ---- gate by input features and store; lane covers channels {2n,2n+1}
        //      of voxels base + quad*4 + r  (rows are L1-hot from the A load)
        #pragma unroll
        for (int r = 0; r < 4; ++r) {
            int vrow = base + quad * 4 + r;
            f32x2 fv = *(const f32x2*)(feat + vrow * 32 + 2 * n);
            f32x2 ov = { acc0[r] * fv[0], acc1[r] * fv[1] };
            *(f32x2*)(out + vrow * 32 + 2 * n) = ov;
        }

        #pragma unroll
        for (int a = 0; a < 3; ++a) { ip[a] = ipn[a]; inx[a] = inn[a]; }
    }
}

extern "C" void kernel_launch(void* const* d_in, const int* in_sizes, int n_in,
                              void* d_out, int out_size, void* d_ws, size_t ws_size,
                              hipStream_t stream) {
    const float* feat  = (const float*)d_in[0];
    const int*   nprev = (const int*)d_in[1];
    const int*   nnext = (const int*)d_in[2];
    const float* Wt    = (const float*)d_in[3];
    const float* gma   = (const float*)d_in[4];
    const float* bta   = (const float*)d_in[5];
    const float* mea   = (const float*)d_in[6];
    const float* var   = (const float*)d_in[7];
    float*       o     = (float*)d_out;

    recon_kernel<<<NBLOCKS, 256, 0, stream>>>(feat, nprev, nnext, Wt,
                                              gma, bta, mea, var, o);
}

// Round 3
// 317.018 us; speedup vs baseline: 1.0281x; 1.0281x over previous
//
#include <hip/hip_runtime.h>
#include <stdint.h>

// ReconBlock: 3-axis 3-tap submanifold conv (gathered neighbors) + BN(inference)
// + sigmoid per branch, branches summed, gated by input features.
// fp32 in/out; compute via bf16 MFMA (16x16x32).
//
// R3: prep kernel pre-converts W -> bf16 in B-fragment lane order (18 KB in ws,
// coalesced dwordx4 reload) and folds BN+log2e into (A,B) so sigmoid =
// rcp(1+exp2(fma(c,A,B))). Main kernel TPW=2 -> 31250 waves for latency hiding.

typedef __attribute__((ext_vector_type(8))) __bf16 bf16x8;
typedef __attribute__((ext_vector_type(8))) unsigned short u16x8;
typedef __attribute__((ext_vector_type(4))) float f32x4;
typedef __attribute__((ext_vector_type(2))) float f32x2;

constexpr int NVOX    = 1000000;
constexpr int NTILES  = NVOX / 16;                  // 62500
constexpr int TPW     = 2;                          // tiles per wave
constexpr int WPB     = 4;                          // waves per block
constexpr int NWAVES  = (NTILES + TPW - 1) / TPW;   // 31250
constexpr int NBLOCKS = (NWAVES + WPB - 1) / WPB;   // 7813
constexpr float LOG2E = 1.4426950408889634f;

// ws layout: bf16 W frags [18][64][8] (18432 B), then A[3][32], B[3][32] fp32
constexpr int WS_WELEMS = 18 * 64 * 8;              // 9216 bf16 elems

__global__ __launch_bounds__(256) void prep_kernel(
    const float* __restrict__ Wt,    // [3][3][32][32]
    const float* __restrict__ gma, const float* __restrict__ bta,
    const float* __restrict__ mea, const float* __restrict__ var,
    unsigned short* __restrict__ wsW, float* __restrict__ wsA,
    float* __restrict__ wsB)
{
    int tid = blockIdx.x * 256 + threadIdx.x;
    if (tid < WS_WELEMS) {
        int f    = tid >> 9;          // fragment id = (br*3+t)*2+h
        int rem  = tid & 511;
        int lane = rem >> 3;
        int j    = rem & 7;
        int br = f / 6, t = (f >> 1) % 3, h = f & 1;
        int n = lane & 15, quad = lane >> 4;
        // B[k=quad*8+j][col]; col interleave: half h = original channel 2n+h
        float w = Wt[((br * 3 + t) * 32 + quad * 8 + j) * 32 + 2 * n + h];
        union { float f; unsigned u; } c; c.f = w;
        wsW[(f * 64 + lane) * 8 + j] = (unsigned short)((c.u + 0x8000u) >> 16);
    } else if (tid < WS_WELEMS + 96) {
        int i = tid - WS_WELEMS;      // br*32 + c
        float s = gma[i] * __frsqrt_rn(var[i] + 1e-5f);
        wsA[i] = -s * LOG2E;
        wsB[i] = (mea[i] * s - bta[i]) * LOG2E;
    }
}

__device__ __forceinline__ unsigned pack_bf(float a, float b) {
    union { float f; unsigned u; } ca, cb; ca.f = a; cb.f = b;
    // d = hi16(a+0x8000) | hi16(b+0x8000)<<16  (one v_perm)
    return __builtin_amdgcn_perm(cb.u + 0x8000u, ca.u + 0x8000u, 0x07060302u);
}
__device__ __forceinline__ bf16x8 cvt_frag(f32x4 lo, f32x4 hi) {
    union { unsigned u[4]; bf16x8 v; } r;
    r.u[0] = pack_bf(lo[0], lo[1]); r.u[1] = pack_bf(lo[2], lo[3]);
    r.u[2] = pack_bf(hi[0], hi[1]); r.u[3] = pack_bf(hi[2], hi[3]);
    return r.v;
}

__global__ __launch_bounds__(256) void recon_kernel(
    const float*          __restrict__ feat,   // [N][32]
    const int*            __restrict__ nprev,  // [3][N]
    const int*            __restrict__ nnext,  // [3][N]
    const unsigned short* __restrict__ wsW,    // [18][64][8] bf16
    const float*          __restrict__ wsA,    // [3][32]
    const float*          __restrict__ wsB,    // [3][32]
    float*                __restrict__ out)    // [N][32]
{
    const int lane = threadIdx.x & 63;
    const int n    = lane & 15;   // lane owns out channels 2n, 2n+1
    const int quad = lane >> 4;

    // XCD-aware swizzle: contiguous 1/8th of voxel range per XCD so z-axis
    // gather windows (~±270 KB) stay in one XCD's L2 stream.
    int b   = blockIdx.x;
    int per = NBLOCKS / 8;
    int bs  = (b < per * 8) ? ((b & 7) * per + (b >> 3)) : b;
    int wv  = bs * WPB + (threadIdx.x >> 6);

    const int t0 = wv * TPW;
    if (t0 >= NTILES) return;

    // ---- W fragments: 18 coalesced dwordx4 loads, L1/L2-hot (18 KB total)
    bf16x8 Bf[18];
    #pragma unroll
    for (int f = 0; f < 18; ++f)
        Bf[f] = __builtin_bit_cast(bf16x8, *(const u16x8*)(wsW + (f * 64 + lane) * 8));

    // ---- folded BN consts for this lane's channels (2n, 2n+1)
    f32x2 A_[3], B_[3];
    #pragma unroll
    for (int br = 0; br < 3; ++br) {
        A_[br] = *(const f32x2*)(wsA + br * 32 + 2 * n);
        B_[br] = *(const f32x2*)(wsB + br * 32 + 2 * n);
    }

    // ---- neighbor indices for first tile (prefetched one tile ahead below)
    int ip[3], inx[3];
    {
        int row0 = t0 * 16 + n;
        #pragma unroll
        for (int a = 0; a < 3; ++a) {
            ip[a]  = nprev[a * NVOX + row0];
            inx[a] = nnext[a * NVOX + row0];
        }
    }

    #pragma unroll 1
    for (int tt = 0; tt < TPW; ++tt) {
        int tile = t0 + tt;
        if (tile >= NTILES) break;
        int base = tile * 16;
        int row  = base + n;

        // ---- issue all A loads (self + 3 prev + 3 next), 32 B each
        const f32x4* ps = (const f32x4*)(feat + row * 32 + quad * 8);
        f32x4 s_lo = ps[0], s_hi = ps[1];
        f32x4 p_lo[3], p_hi[3], n_lo[3], n_hi[3];
        #pragma unroll
        for (int a = 0; a < 3; ++a) {
            p_lo[a] = (f32x4){0.f, 0.f, 0.f, 0.f}; p_hi[a] = p_lo[a];
            n_lo[a] = p_lo[a];                     n_hi[a] = p_lo[a];
            if (ip[a] >= 0) {
                const f32x4* pp = (const f32x4*)(feat + ip[a] * 32 + quad * 8);
                p_lo[a] = pp[0]; p_hi[a] = pp[1];
            }
            if (inx[a] >= 0) {
                const f32x4* pn = (const f32x4*)(feat + inx[a] * 32 + quad * 8);
                n_lo[a] = pn[0]; n_hi[a] = pn[1];
            }
        }

        // ---- prefetch next tile's neighbor indices while gathers in flight
        int ipn[3], inn[3];
        if (tt + 1 < TPW && tile + 1 < NTILES) {
            int nrow = row + 16;
            #pragma unroll
            for (int a = 0; a < 3; ++a) {
                ipn[a] = nprev[a * NVOX + nrow];
                inn[a] = nnext[a * NVOX + nrow];
            }
        } else {
            #pragma unroll
            for (int a = 0; a < 3; ++a) { ipn[a] = -1; inn[a] = -1; }
        }

        // ---- convert to bf16 fragments (v_perm pack, 3 ops / 2 elems)
        bf16x8 Aself = cvt_frag(s_lo, s_hi);
        bf16x8 Ap[3], An[3];
        #pragma unroll
        for (int a = 0; a < 3; ++a) {
            Ap[a] = cvt_frag(p_lo[a], p_hi[a]);
            An[a] = cvt_frag(n_lo[a], n_hi[a]);
        }

        // ---- 3 branches x (3 taps x 2 halves) MFMA, BN+sigmoid via exp2, sum
        f32x4 acc0 = {0.f, 0.f, 0.f, 0.f}, acc1 = {0.f, 0.f, 0.f, 0.f};
        #pragma unroll
        for (int br = 0; br < 3; ++br) {
            f32x4 c0 = {0.f, 0.f, 0.f, 0.f}, c1 = {0.f, 0.f, 0.f, 0.f};
            c0 = __builtin_amdgcn_mfma_f32_16x16x32_bf16(Ap[br], Bf[br*6 + 0], c0, 0, 0, 0);
            c1 = __builtin_amdgcn_mfma_f32_16x16x32_bf16(Ap[br], Bf[br*6 + 1], c1, 0, 0, 0);
            c0 = __builtin_amdgcn_mfma_f32_16x16x32_bf16(Aself,  Bf[br*6 + 2], c0, 0, 0, 0);
            c1 = __builtin_amdgcn_mfma_f32_16x16x32_bf16(Aself,  Bf[br*6 + 3], c1, 0, 0, 0);
            c0 = __builtin_amdgcn_mfma_f32_16x16x32_bf16(An[br], Bf[br*6 + 4], c0, 0, 0, 0);
            c1 = __builtin_amdgcn_mfma_f32_16x16x32_bf16(An[br], Bf[br*6 + 5], c1, 0, 0, 0);
            float a0 = A_[br][0], b0 = B_[br][0], a1 = A_[br][1], b1 = B_[br][1];
            #pragma unroll
            for (int r = 0; r < 4; ++r) {
                float e0 = __builtin_amdgcn_exp2f(__builtin_fmaf(c0[r], a0, b0));
                float e1 = __builtin_amdgcn_exp2f(__builtin_fmaf(c1[r], a1, b1));
                acc0[r] += __builtin_amdgcn_rcpf(1.0f + e0);
                acc1[r] += __builtin_amdgcn_rcpf(1.0f + e1);
            }
        }

        // ---- gate by input features and store; rows are L1-hot from A loads
        #pragma unroll
        for (int r = 0; r < 4; ++r) {
            int vrow = base + quad * 4 + r;
            f32x2 fv = *(const f32x2*)(feat + vrow * 32 + 2 * n);
            f32x2 ov = { acc0[r] * fv[0], acc1[r] * fv[1] };
            *(f32x2*)(out + vrow * 32 + 2 * n) = ov;
        }

        #pragma unroll
        for (int a = 0; a < 3; ++a) { ip[a] = ipn[a]; inx[a] = inn[a]; }
    }
}

extern "C" void kernel_launch(void* const* d_in, const int* in_sizes, int n_in,
                              void* d_out, int out_size, void* d_ws, size_t ws_size,
                              hipStream_t stream) {
    const float* feat  = (const float*)d_in[0];
    const int*   nprev = (const int*)d_in[1];
    const int*   nnext = (const int*)d_in[2];
    const float* Wt    = (const float*)d_in[3];
    const float* gma   = (const float*)d_in[4];
    const float* bta   = (const float*)d_in[5];
    const float* mea   = (const float*)d_in[6];
    const float* var   = (const float*)d_in[7];
    float*       o     = (float*)d_out;

    unsigned short* wsW = (unsigned short*)d_ws;
    float*          wsA = (float*)((char*)d_ws + WS_WELEMS * 2);
    float*          wsB = wsA + 96;

    prep_kernel<<<(WS_WELEMS + 96 + 255) / 256, 256, 0, stream>>>(
        Wt, gma, bta, mea, var, wsW, wsA, wsB);
    recon_kernel<<<NBLOCKS, 256, 0, stream>>>(feat, nprev, nnext,
                                              wsW, wsA, wsB, o);
}